// Round 14
// baseline (961.460 us; speedup 1.0000x reference)
//
#include <hip/hip_runtime.h>
#include <hip/hip_bf16.h>

// Problem constants
#define H_    128
#define IN_   93
#define NL_   4
#define B_    256
#define T_    512
#define G_    512   // 4*H
#define C_    32    // chunk length (timesteps per pipeline stage)
#define NCH   (T_ / C_)          // 16 chunks
#define LOG2E 1.44269504088896f
#define BH_   (B_ * H_)          // 32768
#define B96_  (B_ * 96)

typedef __attribute__((ext_vector_type(8))) short bf16x8;
typedef __attribute__((ext_vector_type(4))) float f32x4;
typedef unsigned long long u64;

#define RCHUNK ((size_t)C_ * BH_)   // elems per ring slot (one chunk of h)

__device__ __forceinline__ ushort bf16_rn(float f) {
    uint x = __float_as_uint(f);
    uint r = (x + 0x7FFFu + ((x >> 16) & 1u)) >> 16;
    return (ushort)r;
}
__device__ __forceinline__ float exp2_fast(float x) { return __builtin_amdgcn_exp2f(x); }
__device__ __forceinline__ float rcp_fast(float x)  { return __builtin_amdgcn_rcpf(x); }

__device__ __forceinline__ void spin_acq(int* p, int target) {
    int v = __hip_atomic_load(p, __ATOMIC_ACQUIRE, __HIP_MEMORY_SCOPE_AGENT);
    while (v < target) {
        __builtin_amdgcn_s_sleep(2);
        v = __hip_atomic_load(p, __ATOMIC_ACQUIRE, __HIP_MEMORY_SCOPE_AGENT);
    }
}

// ---------------------------------------------------------------------------
// prep_x: x [B][T][93] f32 -> xb [T][B][96] bf16 (zero-padded)
// ---------------------------------------------------------------------------
__global__ void prep_x(const float* __restrict__ x, ushort* __restrict__ xb) {
    int idx = blockIdx.x * 256 + threadIdx.x;
    int t = idx / (B_ * 96);
    int rem = idx % (B_ * 96);
    int b = rem / 96;
    int k = rem % 96;
    float v = 0.0f;
    if (k < IN_) v = x[((size_t)b * T_ + t) * IN_ + k];
    xb[idx] = bf16_rn(v);
}

// ---------------------------------------------------------------------------
// prep_w: combined prescaled bf16 weights Wc [NL][512][256]
// ---------------------------------------------------------------------------
__global__ void prep_w(const float* __restrict__ Wih0,
                       const float* __restrict__ Wihr,
                       const float* __restrict__ Whh,
                       ushort* __restrict__ Wc) {
    int idx = blockIdx.x * 256 + threadIdx.x;
    int l = idx / (G_ * 256);
    int rem = idx % (G_ * 256);
    int g = rem / 256;
    int k = rem % 256;
    int kx = (l == 0) ? 96 : 128;
    float v = 0.0f;
    if (k < kx) {
        if (l == 0) { if (k < IN_) v = Wih0[g * IN_ + k]; }
        else        { v = Wihr[(((size_t)(l - 1)) * G_ + g) * H_ + k]; }
    } else if (k < kx + H_) {
        v = Whh[(((size_t)l) * G_ + g) * H_ + (k - kx)];
    }
    float scale = (g >= 256 && g < 384) ? (2.0f * LOG2E) : LOG2E;
    Wc[idx] = bf16_rn(v * scale);
}

__global__ void prep_bias(const float* __restrict__ bih,
                          const float* __restrict__ bhh,
                          float* __restrict__ bc) {
    int idx = blockIdx.x * 256 + threadIdx.x;
    int g = idx & 511;
    float scale = (g >= 256 && g < 384) ? (2.0f * LOG2E) : LOG2E;
    bc[idx] = (bih[idx] + bhh[idx]) * scale;
}

__global__ void zero_flags(int* __restrict__ fl) {
    if (threadIdx.x < 128) fl[threadIdx.x] = 0;
}

// ---------------------------------------------------------------------------
// recur_persist: ONE launch, 64 persistent blocks (l,g), 1 block/CU.
// Round-11 structure exactly (C=32, rolled loop, SWZ16, chunk handshake,
// 8-trans epilogue). NEW: h-MFMA accumulation split into two independent
// 2-deep chains per gate (ac: s=0,1; hc: s=2,3; ac+=hc) — halves the MFMA
// dependent-latency segment of the per-step recurrence critical path.
// ---------------------------------------------------------------------------
#define SWZ16(row, col) ((col) ^ (((row) & 15) << 3))   // ushort-index swizzle
#define XRD(ts, s) (*(const bf16x8*)&hist[(ts) * 2048 + lo * 128 + \
                     ((((s) << 5) | (q << 3)) ^ (lo << 3))])
#define HRD(ptr, s) (*(const bf16x8*)&(ptr)[lo * 128 + \
                     ((((s) << 5) | (q << 3)) ^ (lo << 3))])
#define MF(a, av, bw) a = __builtin_amdgcn_mfma_f32_16x16x32_bf16(av, bw, a, 0, 0, 0)

__global__ __launch_bounds__(512, 1)
void recur_persist(const ushort* __restrict__ xb,
                   const ushort* __restrict__ Wc,
                   const float* __restrict__ biasc,
                   ushort* __restrict__ ring,   // [3][2] slots of RCHUNK
                   int*    __restrict__ flags,  // [0..63]=prog, [64..127]=cons
                   const float* __restrict__ wfc,
                   const float* __restrict__ bfc,
                   float* __restrict__ out) {
    __shared__ ushort hist[C_ * 16 * 128];   // 128 KiB, swizzled [t][row][col]
    __shared__ ushort seedb[16 * 128];       // 4 KiB, swizzled
    __shared__ float  wfs[H_];

    const int bid = blockIdx.x;
    const int l = bid >> 4;
    const int g = bid & 15;
    const bool lz = (l == 0);

    const int tid = threadIdx.x;
    const int wv  = tid >> 6;
    const int ln  = tid & 63;
    const int q   = ln >> 4;
    const int lo  = ln & 15;
    const int u   = (wv << 4) | lo;
    const int b0  = g << 4;

    const ushort* Wl = Wc + (size_t)l * G_ * 256;
    const float*  bl = biasc + l * G_;
    const int kx = lz ? 96 : 128;

    int* prog = flags;
    int* cons = flags + 64;
    int* pself = prog + (l * 16 + g);
    int* pup   = prog + ((l - 1) * 16 + g);   // valid l>0
    int* cself = cons + (l * 16 + g);
    int* cdown = cons + ((l + 1) * 16 + g);   // valid l<3

    if (tid < H_) wfs[tid] = wfc[tid];
    ((u64*)seedb)[tid] = 0ull;   // all 512 u64s: full 16x128 seed = 0
    const float bfc0 = bfc[0];

    // ---- persistent weights (x-part cols 0.., h-part cols kx..)
    bf16x8 bwx[4][4], bwh[4][4];
#pragma unroll
    for (int tu = 0; tu < 4; ++tu)
#pragma unroll
        for (int s = 0; s < 4; ++s) {
            const ushort* rowp = Wl + ((size_t)((tu << 7) + u) << 8);
            bwx[tu][s] = *(const bf16x8*)(rowp + (s << 5) + (q << 3));
            bwh[tu][s] = *(const bf16x8*)(rowp + kx + (s << 5) + (q << 3));
        }
    const float bv0 = bl[u];
    const float bv1 = bl[128 + u];
    const float bv2 = bl[256 + u];
    const float bv3 = bl[384 + u];

    f32x4 cc = {0.0f, 0.0f, 0.0f, 0.0f};

    for (int k = 0; k < NCH; ++k) {
        const int t0 = k * C_;
        ushort* ring_self = ring + (size_t)(2 * l + (k & 1)) * RCHUNK;
        const ushort* ring_up = ring + (size_t)(2 * (l - 1) + (k & 1)) * RCHUNK;

        // ---- ingest gate: upstream chunk k published (acquire -> cache inval)
        if (l > 0) spin_acq(pup, k + 1);

        // ---- bulk-in: chunk k -> hist (reg-staged, swizzled)
        for (int i = tid; i < C_ * 16 * 32; i += 512) {
            int t = i >> 9, rem = i & 511, row = rem >> 5, c8 = rem & 31;
            u64 v = 0;
            if (lz) {
                if (c8 < 24)
                    v = *(const u64*)(xb + (size_t)(t0 + t) * B96_ +
                                      (size_t)(b0 + row) * 96 + (c8 << 2));
            } else {
                v = *(const u64*)(ring_up + (size_t)t * BH_ +
                                  (size_t)(b0 + row) * H_ + (c8 << 2));
            }
            *(u64*)&hist[t * 2048 + row * 128 + SWZ16(row, c8 << 2)] = v;
        }
        __syncthreads();   // loads done + LDS visible (drains vmcnt+lgkm)
        if (tid == 0 && l > 0)
            __hip_atomic_store(cself, k + 1, __ATOMIC_RELAXED, __HIP_MEMORY_SCOPE_AGENT);

        // ---- prime: x-gates for step 0
        f32x4 ac0 = {bv0, bv0, bv0, bv0};
        f32x4 ac1 = {bv1, bv1, bv1, bv1};
        f32x4 ac2 = {bv2, bv2, bv2, bv2};
        f32x4 ac3 = {bv3, bv3, bv3, bv3};
        {
            bf16x8 x0 = XRD(0, 0), x1 = XRD(0, 1), x2 = XRD(0, 2), x3 = XRD(0, 3);
            MF(ac0, x0, bwx[0][0]); MF(ac1, x0, bwx[1][0]); MF(ac2, x0, bwx[2][0]); MF(ac3, x0, bwx[3][0]);
            MF(ac0, x1, bwx[0][1]); MF(ac1, x1, bwx[1][1]); MF(ac2, x1, bwx[2][1]); MF(ac3, x1, bwx[3][1]);
            MF(ac0, x2, bwx[0][2]); MF(ac1, x2, bwx[1][2]); MF(ac2, x2, bwx[2][2]); MF(ac3, x2, bwx[3][2]);
            MF(ac0, x3, bwx[0][3]); MF(ac1, x3, bwx[1][3]); MF(ac2, x3, bwx[2][3]); MF(ac3, x3, bwx[3][3]);
        }

        // ---- 32 steps, LDS/registers only
        for (int t = 0; t < C_; ++t) {
            asm volatile("s_waitcnt lgkmcnt(0)" ::: "memory");
            __builtin_amdgcn_s_barrier();
            __builtin_amdgcn_sched_barrier(0);

            const ushort* hsrc = (t == 0) ? seedb : &hist[(t - 1) * 2048];
            bf16x8 h0 = HRD(hsrc, 0), h1 = HRD(hsrc, 1), h2 = HRD(hsrc, 2), h3v = HRD(hsrc, 3);

            // split accumulation: ac chain (s=0,1) || hc chain (s=2,3), then add
            const f32x4 zz = {0.0f, 0.0f, 0.0f, 0.0f};
            f32x4 hc0 = zz, hc1 = zz, hc2 = zz, hc3 = zz;
            MF(ac0, h0, bwh[0][0]); MF(ac1, h0, bwh[1][0]); MF(ac2, h0, bwh[2][0]); MF(ac3, h0, bwh[3][0]);
            MF(hc0, h2, bwh[0][2]); MF(hc1, h2, bwh[1][2]); MF(hc2, h2, bwh[2][2]); MF(hc3, h2, bwh[3][2]);
            MF(ac0, h1, bwh[0][1]); MF(ac1, h1, bwh[1][1]); MF(ac2, h1, bwh[2][1]); MF(ac3, h1, bwh[3][1]);
            MF(hc0, h3v, bwh[0][3]); MF(hc1, h3v, bwh[1][3]); MF(hc2, h3v, bwh[2][3]); MF(hc3, h3v, bwh[3][3]);
            ac0 += hc0; ac1 += hc1; ac2 += hc2; ac3 += hc3;

            f32x4 an0 = {bv0, bv0, bv0, bv0};
            f32x4 an1 = {bv1, bv1, bv1, bv1};
            f32x4 an2 = {bv2, bv2, bv2, bv2};
            f32x4 an3 = {bv3, bv3, bv3, bv3};
            if (t + 1 < C_) {
                bf16x8 x0 = XRD(t + 1, 0), x1 = XRD(t + 1, 1), x2 = XRD(t + 1, 2), x3 = XRD(t + 1, 3);
                MF(an0, x0, bwx[0][0]); MF(an1, x0, bwx[1][0]); MF(an2, x0, bwx[2][0]); MF(an3, x0, bwx[3][0]);
                MF(an0, x1, bwx[0][1]); MF(an1, x1, bwx[1][1]); MF(an2, x1, bwx[2][1]); MF(an3, x1, bwx[3][1]);
                MF(an0, x2, bwx[0][2]); MF(an1, x2, bwx[1][2]); MF(an2, x2, bwx[2][2]); MF(an3, x2, bwx[3][2]);
                MF(an0, x3, bwx[0][3]); MF(an1, x3, bwx[1][3]); MF(an2, x3, bwx[2][3]); MF(an3, x3, bwx[3][3]);
            }

            // cell update (round-11 epilogue; ei/eo graceful, eg/ec clamped)
#pragma unroll
            for (int r = 0; r < 4; ++r) {
                float ei = exp2_fast(-ac0[r]);
                float ef = exp2_fast(-ac1[r]);
                float eg = exp2_fast(fminf(-ac2[r], 60.0f));
                float eo = exp2_fast(-ac3[r]);
                float rf  = rcp_fast(1.0f + ef);
                float rig = rcp_fast((1.0f + ei) * (1.0f + eg));
                float cn  = __builtin_fmaf(cc[r], rf, (1.0f - eg) * rig);
                cc[r] = cn;
                float ec  = exp2_fast(fminf(-2.88539008177793f * cn, 60.0f));
                float roc = rcp_fast((1.0f + eo) * (1.0f + ec));
                float h_  = (1.0f - ec) * roc;
                int row = (q << 2) + r;
                hist[t * 2048 + row * 128 + SWZ16(row, u)] = bf16_rn(h_);
            }
            ac0 = an0; ac1 = an1; ac2 = an2; ac3 = an3;
        }

        // ---- chunk end: all h writes visible
        asm volatile("s_waitcnt lgkmcnt(0)" ::: "memory");
        __builtin_amdgcn_s_barrier();
        __builtin_amdgcn_sched_barrier(0);

        // seed for next chunk (LDS->LDS before hist is overwritten)
        {
            int row = tid >> 5, c8 = tid & 31;
            u64 v = *(const u64*)&hist[(C_ - 1) * 2048 + row * 128 + SWZ16(row, c8 << 2)];
            *(u64*)&seedb[row * 128 + SWZ16(row, c8 << 2)] = v;
        }

        // slot-free gate: consumer ingested chunk k-2 (slot k&1 reusable)
        if (l < 3 && k >= 2) spin_acq(cdown, k - 1);

        // bulk-out
        if (l < 3) {
            for (int i = tid; i < C_ * 16 * 32; i += 512) {
                int t = i >> 9, rem = i & 511, row = rem >> 5, c8 = rem & 31;
                u64 v = *(const u64*)&hist[t * 2048 + row * 128 + SWZ16(row, c8 << 2)];
                *(u64*)(ring_self + (size_t)t * BH_ +
                        (size_t)(b0 + row) * H_ + (c8 << 2)) = v;
            }
        } else {
            // fused FC straight from LDS: thread -> (t, batch-row)
            int t = tid >> 4, row = tid & 15;
            float acc = 0.0f;
#pragma unroll 8
            for (int c8 = 0; c8 < 32; ++c8) {
                u64 v = *(const u64*)&hist[t * 2048 + row * 128 + SWZ16(row, c8 << 2)];
#pragma unroll
                for (int j = 0; j < 4; ++j) {
                    float hvf = __uint_as_float(((uint)(ushort)(v >> (16 * j))) << 16);
                    acc = __builtin_fmaf(hvf, wfs[(c8 << 2) + j], acc);
                }
            }
            float z = acc + bfc0;
            out[(size_t)(b0 + row) * T_ + (t0 + t)] =
                rcp_fast(1.0f + exp2_fast(-z * LOG2E));
        }

        __syncthreads();   // drains stores (vmcnt) + hist reads done, all waves
        if (tid == 0 && l < 3)
            __hip_atomic_store(pself, k + 1, __ATOMIC_RELEASE, __HIP_MEMORY_SCOPE_AGENT);
    }
}

// ---------------------------------------------------------------------------
extern "C" void kernel_launch(void* const* d_in, const int* in_sizes, int n_in,
                              void* d_out, int out_size, void* d_ws, size_t ws_size,
                              hipStream_t stream) {
    const float* x    = (const float*)d_in[0];
    const float* Wih0 = (const float*)d_in[1];
    const float* Wihr = (const float*)d_in[2];
    const float* Whh  = (const float*)d_in[3];
    const float* bih  = (const float*)d_in[4];
    const float* bhh  = (const float*)d_in[5];
    const float* Wfc  = (const float*)d_in[6];
    const float* bfc  = (const float*)d_in[7];
    float* out = (float*)d_out;

    char* ws = (char*)d_ws;
    const size_t xb_bytes    = (size_t)T_ * B_ * 96 * 2;        // 25,165,824
    const size_t wc_bytes    = (size_t)NL_ * G_ * 256 * 2;      //  1,048,576
    const size_t bias_bytes  = (size_t)NL_ * G_ * 4;            //      8,192
    const size_t ring_bytes  = (size_t)6 * RCHUNK * 2;          // 12,582,912
    const size_t flag_bytes  = 128 * 4;

    ushort* xb    = (ushort*)ws;
    ushort* Wc    = (ushort*)(ws + xb_bytes);
    float*  biasc = (float*)(ws + xb_bytes + wc_bytes);
    ushort* ring  = (ushort*)(ws + xb_bytes + wc_bytes + bias_bytes);
    int*    flags = (int*)(ws + xb_bytes + wc_bytes + bias_bytes + ring_bytes);
    (void)flag_bytes;

    prep_x<<<(T_ * B_ * 96) / 256, 256, 0, stream>>>(x, xb);
    prep_w<<<(NL_ * G_ * 256) / 256, 256, 0, stream>>>(Wih0, Wihr, Whh, Wc);
    prep_bias<<<(NL_ * G_) / 256, 256, 0, stream>>>(bih, bhh, biasc);
    zero_flags<<<1, 256, 0, stream>>>(flags);

    recur_persist<<<NL_ * 16, 512, 0, stream>>>(xb, Wc, biasc, ring, flags,
                                                Wfc, bfc, out);
}

// Round 15
// 887.253 us; speedup vs baseline: 1.0836x; 1.0836x over previous
//
#include <hip/hip_runtime.h>
#include <hip/hip_bf16.h>

// Problem constants
#define H_    128
#define IN_   93
#define NL_   4
#define B_    256
#define T_    512
#define G_    512   // 4*H
#define C_    32    // chunk length (timesteps per pipeline stage)
#define NCH   (T_ / C_)          // 16 chunks
#define LOG2E 1.44269504088896f
#define BH_   (B_ * H_)          // 32768
#define B96_  (B_ * 96)

typedef __attribute__((ext_vector_type(8))) short bf16x8;
typedef __attribute__((ext_vector_type(4))) float f32x4;
typedef unsigned long long u64;

#define RCHUNK ((size_t)C_ * BH_)   // elems per ring slot (one chunk of h)

__device__ __forceinline__ ushort bf16_rn(float f) {
    uint x = __float_as_uint(f);
    uint r = (x + 0x7FFFu + ((x >> 16) & 1u)) >> 16;
    return (ushort)r;
}
__device__ __forceinline__ float exp2_fast(float x) { return __builtin_amdgcn_exp2f(x); }
__device__ __forceinline__ float rcp_fast(float x)  { return __builtin_amdgcn_rcpf(x); }

__device__ __forceinline__ void spin_acq(int* p, int target) {
    int v = __hip_atomic_load(p, __ATOMIC_ACQUIRE, __HIP_MEMORY_SCOPE_AGENT);
    while (v < target) {
        __builtin_amdgcn_s_sleep(2);
        v = __hip_atomic_load(p, __ATOMIC_ACQUIRE, __HIP_MEMORY_SCOPE_AGENT);
    }
}

// ---------------------------------------------------------------------------
// prep_x: x [B][T][93] f32 -> xb [T][B][96] bf16 (zero-padded)
// ---------------------------------------------------------------------------
__global__ void prep_x(const float* __restrict__ x, ushort* __restrict__ xb) {
    int idx = blockIdx.x * 256 + threadIdx.x;
    int t = idx / (B_ * 96);
    int rem = idx % (B_ * 96);
    int b = rem / 96;
    int k = rem % 96;
    float v = 0.0f;
    if (k < IN_) v = x[((size_t)b * T_ + t) * IN_ + k];
    xb[idx] = bf16_rn(v);
}

// ---------------------------------------------------------------------------
// prep_w: combined prescaled bf16 weights Wc [NL][512][256]
// ---------------------------------------------------------------------------
__global__ void prep_w(const float* __restrict__ Wih0,
                       const float* __restrict__ Wihr,
                       const float* __restrict__ Whh,
                       ushort* __restrict__ Wc) {
    int idx = blockIdx.x * 256 + threadIdx.x;
    int l = idx / (G_ * 256);
    int rem = idx % (G_ * 256);
    int g = rem / 256;
    int k = rem % 256;
    int kx = (l == 0) ? 96 : 128;
    float v = 0.0f;
    if (k < kx) {
        if (l == 0) { if (k < IN_) v = Wih0[g * IN_ + k]; }
        else        { v = Wihr[(((size_t)(l - 1)) * G_ + g) * H_ + k]; }
    } else if (k < kx + H_) {
        v = Whh[(((size_t)l) * G_ + g) * H_ + (k - kx)];
    }
    float scale = (g >= 256 && g < 384) ? (2.0f * LOG2E) : LOG2E;
    Wc[idx] = bf16_rn(v * scale);
}

__global__ void prep_bias(const float* __restrict__ bih,
                          const float* __restrict__ bhh,
                          float* __restrict__ bc) {
    int idx = blockIdx.x * 256 + threadIdx.x;
    int g = idx & 511;
    float scale = (g >= 256 && g < 384) ? (2.0f * LOG2E) : LOG2E;
    bc[idx] = (bih[idx] + bhh[idx]) * scale;
}

__global__ void zero_flags(int* __restrict__ fl) {
    if (threadIdx.x < 128) fl[threadIdx.x] = 0;
}

// ---------------------------------------------------------------------------
// recur_persist: ONE launch, 64 persistent blocks (l,g), 1 block/CU (LDS cap).
// Each block runs its 16 chunks; inter-layer handoff once per chunk via
// acquire-spin / release-publish on prog[] (produced) and cons[] (ingested).
// Weights+bias+cc loaded ONCE. Step loop: zero global ops, one raw barrier.
// LDS swizzle SWZ16 (row&15): b128 reads 2-way-free, h-writes ~2-way.
// [ROUND 15: byte-exact revert to the round-11 kernel (887 us best).
//  Rounds 12 (C=16+unroll), 13 (merged rcp), 14 (split MFMA chains) all
//  regressed -> step time is recurrence-latency-pinned, not throughput.]
// ---------------------------------------------------------------------------
#define SWZ16(row, col) ((col) ^ (((row) & 15) << 3))   // ushort-index swizzle
#define XRD(ts, s) (*(const bf16x8*)&hist[(ts) * 2048 + lo * 128 + \
                     ((((s) << 5) | (q << 3)) ^ (lo << 3))])
#define HRD(ptr, s) (*(const bf16x8*)&(ptr)[lo * 128 + \
                     ((((s) << 5) | (q << 3)) ^ (lo << 3))])
#define MF(a, av, bw) a = __builtin_amdgcn_mfma_f32_16x16x32_bf16(av, bw, a, 0, 0, 0)

__global__ __launch_bounds__(512, 1)
void recur_persist(const ushort* __restrict__ xb,
                   const ushort* __restrict__ Wc,
                   const float* __restrict__ biasc,
                   ushort* __restrict__ ring,   // [3][2] slots of RCHUNK
                   int*    __restrict__ flags,  // [0..63]=prog, [64..127]=cons
                   const float* __restrict__ wfc,
                   const float* __restrict__ bfc,
                   float* __restrict__ out) {
    __shared__ ushort hist[C_ * 16 * 128];   // 128 KiB, swizzled [t][row][col]
    __shared__ ushort seedb[16 * 128];       // 4 KiB, swizzled
    __shared__ float  wfs[H_];

    const int bid = blockIdx.x;
    const int l = bid >> 4;
    const int g = bid & 15;
    const bool lz = (l == 0);

    const int tid = threadIdx.x;
    const int wv  = tid >> 6;
    const int ln  = tid & 63;
    const int q   = ln >> 4;
    const int lo  = ln & 15;
    const int u   = (wv << 4) | lo;
    const int b0  = g << 4;

    const ushort* Wl = Wc + (size_t)l * G_ * 256;
    const float*  bl = biasc + l * G_;
    const int kx = lz ? 96 : 128;

    int* prog = flags;
    int* cons = flags + 64;
    int* pself = prog + (l * 16 + g);
    int* pup   = prog + ((l - 1) * 16 + g);   // valid l>0
    int* cself = cons + (l * 16 + g);
    int* cdown = cons + ((l + 1) * 16 + g);   // valid l<3

    if (tid < H_) wfs[tid] = wfc[tid];
    ((u64*)seedb)[tid] = 0ull;   // all 512 u64s: full 16x128 seed = 0
    const float bfc0 = bfc[0];

    // ---- persistent weights (x-part cols 0.., h-part cols kx..)
    bf16x8 bwx[4][4], bwh[4][4];
#pragma unroll
    for (int tu = 0; tu < 4; ++tu)
#pragma unroll
        for (int s = 0; s < 4; ++s) {
            const ushort* rowp = Wl + ((size_t)((tu << 7) + u) << 8);
            bwx[tu][s] = *(const bf16x8*)(rowp + (s << 5) + (q << 3));
            bwh[tu][s] = *(const bf16x8*)(rowp + kx + (s << 5) + (q << 3));
        }
    const float bv0 = bl[u];
    const float bv1 = bl[128 + u];
    const float bv2 = bl[256 + u];
    const float bv3 = bl[384 + u];

    f32x4 cc = {0.0f, 0.0f, 0.0f, 0.0f};

    for (int k = 0; k < NCH; ++k) {
        const int t0 = k * C_;
        ushort* ring_self = ring + (size_t)(2 * l + (k & 1)) * RCHUNK;
        const ushort* ring_up = ring + (size_t)(2 * (l - 1) + (k & 1)) * RCHUNK;

        // ---- ingest gate: upstream chunk k published (acquire -> cache inval)
        if (l > 0) spin_acq(pup, k + 1);

        // ---- bulk-in: chunk k -> hist (reg-staged, swizzled)
        for (int i = tid; i < C_ * 16 * 32; i += 512) {
            int t = i >> 9, rem = i & 511, row = rem >> 5, c8 = rem & 31;
            u64 v = 0;
            if (lz) {
                if (c8 < 24)
                    v = *(const u64*)(xb + (size_t)(t0 + t) * B96_ +
                                      (size_t)(b0 + row) * 96 + (c8 << 2));
            } else {
                v = *(const u64*)(ring_up + (size_t)t * BH_ +
                                  (size_t)(b0 + row) * H_ + (c8 << 2));
            }
            *(u64*)&hist[t * 2048 + row * 128 + SWZ16(row, c8 << 2)] = v;
        }
        __syncthreads();   // loads done + LDS visible (drains vmcnt+lgkm)
        if (tid == 0 && l > 0)
            __hip_atomic_store(cself, k + 1, __ATOMIC_RELAXED, __HIP_MEMORY_SCOPE_AGENT);

        // ---- prime: x-gates for step 0
        f32x4 ac0 = {bv0, bv0, bv0, bv0};
        f32x4 ac1 = {bv1, bv1, bv1, bv1};
        f32x4 ac2 = {bv2, bv2, bv2, bv2};
        f32x4 ac3 = {bv3, bv3, bv3, bv3};
        {
            bf16x8 x0 = XRD(0, 0), x1 = XRD(0, 1), x2 = XRD(0, 2), x3 = XRD(0, 3);
            MF(ac0, x0, bwx[0][0]); MF(ac1, x0, bwx[1][0]); MF(ac2, x0, bwx[2][0]); MF(ac3, x0, bwx[3][0]);
            MF(ac0, x1, bwx[0][1]); MF(ac1, x1, bwx[1][1]); MF(ac2, x1, bwx[2][1]); MF(ac3, x1, bwx[3][1]);
            MF(ac0, x2, bwx[0][2]); MF(ac1, x2, bwx[1][2]); MF(ac2, x2, bwx[2][2]); MF(ac3, x2, bwx[3][2]);
            MF(ac0, x3, bwx[0][3]); MF(ac1, x3, bwx[1][3]); MF(ac2, x3, bwx[2][3]); MF(ac3, x3, bwx[3][3]);
        }

        // ---- 32 steps, LDS/registers only
        for (int t = 0; t < C_; ++t) {
            asm volatile("s_waitcnt lgkmcnt(0)" ::: "memory");
            __builtin_amdgcn_s_barrier();
            __builtin_amdgcn_sched_barrier(0);

            const ushort* hsrc = (t == 0) ? seedb : &hist[(t - 1) * 2048];
            bf16x8 h0 = HRD(hsrc, 0), h1 = HRD(hsrc, 1), h2 = HRD(hsrc, 2), h3v = HRD(hsrc, 3);
            MF(ac0, h0, bwh[0][0]); MF(ac1, h0, bwh[1][0]); MF(ac2, h0, bwh[2][0]); MF(ac3, h0, bwh[3][0]);
            MF(ac0, h1, bwh[0][1]); MF(ac1, h1, bwh[1][1]); MF(ac2, h1, bwh[2][1]); MF(ac3, h1, bwh[3][1]);
            MF(ac0, h2, bwh[0][2]); MF(ac1, h2, bwh[1][2]); MF(ac2, h2, bwh[2][2]); MF(ac3, h2, bwh[3][2]);
            MF(ac0, h3v, bwh[0][3]); MF(ac1, h3v, bwh[1][3]); MF(ac2, h3v, bwh[2][3]); MF(ac3, h3v, bwh[3][3]);

            f32x4 an0 = {bv0, bv0, bv0, bv0};
            f32x4 an1 = {bv1, bv1, bv1, bv1};
            f32x4 an2 = {bv2, bv2, bv2, bv2};
            f32x4 an3 = {bv3, bv3, bv3, bv3};
            if (t + 1 < C_) {
                bf16x8 x0 = XRD(t + 1, 0), x1 = XRD(t + 1, 1), x2 = XRD(t + 1, 2), x3 = XRD(t + 1, 3);
                MF(an0, x0, bwx[0][0]); MF(an1, x0, bwx[1][0]); MF(an2, x0, bwx[2][0]); MF(an3, x0, bwx[3][0]);
                MF(an0, x1, bwx[0][1]); MF(an1, x1, bwx[1][1]); MF(an2, x1, bwx[2][1]); MF(an3, x1, bwx[3][1]);
                MF(an0, x2, bwx[0][2]); MF(an1, x2, bwx[1][2]); MF(an2, x2, bwx[2][2]); MF(an3, x2, bwx[3][2]);
                MF(an0, x3, bwx[0][3]); MF(an1, x3, bwx[1][3]); MF(an2, x3, bwx[2][3]); MF(an3, x3, bwx[3][3]);
            }

            // cell update; h_t -> hist[t] (overwrites consumed upstream slot)
#pragma unroll
            for (int r = 0; r < 4; ++r) {
                float ei = exp2_fast(-ac0[r]);
                float ef = exp2_fast(-ac1[r]);
                float eg = exp2_fast(fminf(-ac2[r], 60.0f));
                float eo = exp2_fast(-ac3[r]);
                float rf  = rcp_fast(1.0f + ef);
                float rig = rcp_fast((1.0f + ei) * (1.0f + eg));
                float cn  = __builtin_fmaf(cc[r], rf, (1.0f - eg) * rig);
                cc[r] = cn;
                float ec  = exp2_fast(fminf(-2.88539008177793f * cn, 60.0f));
                float roc = rcp_fast((1.0f + eo) * (1.0f + ec));
                float h_  = (1.0f - ec) * roc;
                int row = (q << 2) + r;
                hist[t * 2048 + row * 128 + SWZ16(row, u)] = bf16_rn(h_);
            }
            ac0 = an0; ac1 = an1; ac2 = an2; ac3 = an3;
        }

        // ---- chunk end: all h writes visible
        asm volatile("s_waitcnt lgkmcnt(0)" ::: "memory");
        __builtin_amdgcn_s_barrier();
        __builtin_amdgcn_sched_barrier(0);

        // seed for next chunk (LDS->LDS before hist is overwritten)
        {
            int row = tid >> 5, c8 = tid & 31;
            u64 v = *(const u64*)&hist[(C_ - 1) * 2048 + row * 128 + SWZ16(row, c8 << 2)];
            *(u64*)&seedb[row * 128 + SWZ16(row, c8 << 2)] = v;
        }

        // slot-free gate: consumer ingested chunk k-2 (slot k&1 reusable)
        if (l < 3 && k >= 2) spin_acq(cdown, k - 1);

        // bulk-out
        if (l < 3) {
            for (int i = tid; i < C_ * 16 * 32; i += 512) {
                int t = i >> 9, rem = i & 511, row = rem >> 5, c8 = rem & 31;
                u64 v = *(const u64*)&hist[t * 2048 + row * 128 + SWZ16(row, c8 << 2)];
                *(u64*)(ring_self + (size_t)t * BH_ +
                        (size_t)(b0 + row) * H_ + (c8 << 2)) = v;
            }
        } else {
            // fused FC straight from LDS: thread -> (t, batch-row)
            int t = tid >> 4, row = tid & 15;
            float acc = 0.0f;
#pragma unroll 8
            for (int c8 = 0; c8 < 32; ++c8) {
                u64 v = *(const u64*)&hist[t * 2048 + row * 128 + SWZ16(row, c8 << 2)];
#pragma unroll
                for (int j = 0; j < 4; ++j) {
                    float hvf = __uint_as_float(((uint)(ushort)(v >> (16 * j))) << 16);
                    acc = __builtin_fmaf(hvf, wfs[(c8 << 2) + j], acc);
                }
            }
            float z = acc + bfc0;
            out[(size_t)(b0 + row) * T_ + (t0 + t)] =
                rcp_fast(1.0f + exp2_fast(-z * LOG2E));
        }

        __syncthreads();   // drains stores (vmcnt) + hist reads done, all waves
        if (tid == 0 && l < 3)
            __hip_atomic_store(pself, k + 1, __ATOMIC_RELEASE, __HIP_MEMORY_SCOPE_AGENT);
    }
}

// ---------------------------------------------------------------------------
extern "C" void kernel_launch(void* const* d_in, const int* in_sizes, int n_in,
                              void* d_out, int out_size, void* d_ws, size_t ws_size,
                              hipStream_t stream) {
    const float* x    = (const float*)d_in[0];
    const float* Wih0 = (const float*)d_in[1];
    const float* Wihr = (const float*)d_in[2];
    const float* Whh  = (const float*)d_in[3];
    const float* bih  = (const float*)d_in[4];
    const float* bhh  = (const float*)d_in[5];
    const float* Wfc  = (const float*)d_in[6];
    const float* bfc  = (const float*)d_in[7];
    float* out = (float*)d_out;

    char* ws = (char*)d_ws;
    const size_t xb_bytes    = (size_t)T_ * B_ * 96 * 2;        // 25,165,824
    const size_t wc_bytes    = (size_t)NL_ * G_ * 256 * 2;      //  1,048,576
    const size_t bias_bytes  = (size_t)NL_ * G_ * 4;            //      8,192
    const size_t ring_bytes  = (size_t)6 * RCHUNK * 2;          // 12,582,912
    const size_t flag_bytes  = 128 * 4;

    ushort* xb    = (ushort*)ws;
    ushort* Wc    = (ushort*)(ws + xb_bytes);
    float*  biasc = (float*)(ws + xb_bytes + wc_bytes);
    ushort* ring  = (ushort*)(ws + xb_bytes + wc_bytes + bias_bytes);
    int*    flags = (int*)(ws + xb_bytes + wc_bytes + bias_bytes + ring_bytes);
    (void)flag_bytes;

    prep_x<<<(T_ * B_ * 96) / 256, 256, 0, stream>>>(x, xb);
    prep_w<<<(NL_ * G_ * 256) / 256, 256, 0, stream>>>(Wih0, Wihr, Whh, Wc);
    prep_bias<<<(NL_ * G_) / 256, 256, 0, stream>>>(bih, bhh, biasc);
    zero_flags<<<1, 256, 0, stream>>>(flags);

    recur_persist<<<NL_ * 16, 512, 0, stream>>>(xb, Wc, biasc, ring, flags,
                                                Wfc, bfc, out);
}